// Round 6
// baseline (221.637 us; speedup 1.0000x reference)
//
#include <hip/hip_runtime.h>
#include <cmath>

// Problem: x [8, 512, 32, 32] fp32. GroupNorm(32) -> QKV 1x1 -> attention -> proj 1x1 -> +x
constexpr int Bsz = 8, Cch = 512, NPIX = 1024;
constexpr int NG = 32, CPG = 16;

typedef __attribute__((ext_vector_type(4))) float f32x4;
typedef __attribute__((ext_vector_type(8))) short s16x8;

#define GLOBAL_AS __attribute__((address_space(1)))
#define LDS_AS __attribute__((address_space(3)))

__device__ inline short f2bf(float f) {  // RNE fp32 -> bf16
  union { float f; unsigned u; } c = {f};
  unsigned r = (c.u + 0x7fffu + ((c.u >> 16) & 1u)) >> 16;
  return (short)r;
}

__device__ inline float wave_reduce_sum(float v) {
#pragma unroll
  for (int off = 32; off > 0; off >>= 1) v += __shfl_xor(v, off, 64);
  return v;
}

// ---- fused: GroupNorm (blocks 0..255) + weight cvt (256..1279) + zero-l (1280) ----
// GroupNorm writes TRANSPOSED bf16 xnt[b][pix][c].
__global__ __launch_bounds__(256) void prep_kernel(
    const float* __restrict__ x, const float* __restrict__ w,
    const float* __restrict__ bb, short* __restrict__ xnt,
    const float* __restrict__ in1, short* __restrict__ out1, int n1,
    const float* __restrict__ in2, short* __restrict__ out2, int n2,
    float* __restrict__ lsum) {
  __shared__ float sm[8];
  if (blockIdx.x == 1280) {  // ---- zero the softmax denominators [8][1024] ----
    float4 z = {0.f, 0.f, 0.f, 0.f};
    float4* p = (float4*)lsum;
#pragma unroll
    for (int i = 0; i < 8; ++i) p[threadIdx.x + i * 256] = z;
    return;
  }
  if (blockIdx.x >= 256) {  // ---- weight fp32 -> bf16 conversion ----
    const int i = ((blockIdx.x - 256) * 256 + threadIdx.x) * 4;
    const float* in = in1;
    short* out = out1;
    int j = i;
    if (i >= n1) { in = in2; out = out2; j = i - n1; }
    if (j + 3 < (i >= n1 ? n2 : n1)) {
      float4 v = *(const float4*)(in + j);
      short o[4] = {f2bf(v.x), f2bf(v.y), f2bf(v.z), f2bf(v.w)};
      *(uint2*)(out + j) = *(const uint2*)o;
    }
    return;
  }
  // ---- GroupNorm ----
  const int bg = blockIdx.x, b = bg >> 5, g = bg & 31;
  const float* xp = x + ((size_t)(b * Cch + g * CPG)) * NPIX;
  float s = 0.f, ss = 0.f;
  for (int i = threadIdx.x * 4; i < CPG * NPIX; i += 1024) {
    float4 v = *(const float4*)(xp + i);
    s += v.x + v.y + v.z + v.w;
    ss += v.x * v.x + v.y * v.y + v.z * v.z + v.w * v.w;
  }
  s = wave_reduce_sum(s);
  ss = wave_reduce_sum(ss);
  const int wv = threadIdx.x >> 6;
  if ((threadIdx.x & 63) == 0) { sm[wv] = s; sm[4 + wv] = ss; }
  __syncthreads();
  const float tsum = sm[0] + sm[1] + sm[2] + sm[3];
  const float tsq = sm[4] + sm[5] + sm[6] + sm[7];
  const float inv_n = 1.0f / (CPG * NPIX);
  const float mean = tsum * inv_n;
  const float rstd = rsqrtf(tsq * inv_n - mean * mean + 1e-5f);
  float wc[CPG], bc[CPG];
#pragma unroll
  for (int c = 0; c < CPG; ++c) {
    wc[c] = w[g * CPG + c] * rstd;
    bc[c] = bb[g * CPG + c] - mean * wc[c];
  }
  // second pass: 4 pixels/thread, float4 reads (fully coalesced), register transpose
  const int p0 = threadIdx.x * 4;
  short ov[4][CPG];
#pragma unroll
  for (int c = 0; c < CPG; ++c) {
    float4 v = *(const float4*)(xp + (size_t)c * NPIX + p0);
    ov[0][c] = f2bf(v.x * wc[c] + bc[c]);
    ov[1][c] = f2bf(v.y * wc[c] + bc[c]);
    ov[2][c] = f2bf(v.z * wc[c] + bc[c]);
    ov[3][c] = f2bf(v.w * wc[c] + bc[c]);
  }
#pragma unroll
  for (int j = 0; j < 4; ++j) {
    short* op = xnt + ((size_t)(b * NPIX + p0 + j)) * Cch + g * CPG;
    *(uint4*)op = *(const uint4*)&ov[j][0];
    *(uint4*)(op + 8) = *(const uint4*)&ov[j][8];
  }
}

// ---------------- bf16 MFMA GEMM (proven 1-phase BK=32 structure) ----------------
// C[m][n] = sum_k A[m][k]*B[n][k], both row-major k-contiguous. 256 thr = 2x2 waves.
// Tiles shrunk to 128x64 / 64x64 so every dispatch has >=1024 blocks (>=4
// blocks/CU): the vmcnt(0) barrier drain (~600-900cy per K-step) is hidden by
// other resident blocks, which R1-R5 showed is the only thing that hides it.
// XCD-chunked block swizzle (T1, bijective, nwg%8==0) kept from R5.
// EPI 0: qkv split -> m<1024: bf16 Cq[n*ldc+m] (+bias); else bf16 C2[(m-1024)*ldc+n] (+bias)
// EPI 1: softmax-fused QK: bf16 C[m*ldc+n] = exp(acc*alpha); row-sums atomicAdd to (float*)C2p
// EPI 2: PV: bf16 C[m*ldc+n] = acc / l[m]   (l passed via resid)
// EPI 3: fp32 C[m*ldc+n] = acc + bias[m] + resid[m*ldc+n]
template <int BM, int BN, int EPI>
__global__ __launch_bounds__(256) void mfma_gemm(
    const short* __restrict__ A, const short* __restrict__ B, int K, int lda,
    int ldb, long sA, long sB, const float* __restrict__ bias, float alpha,
    void* __restrict__ Cp, long sC, int ldc, void* __restrict__ C2p, long sC2,
    const float* __restrict__ resid, long sR) {
  constexpr int FM = BM / 32, FN = BN / 32;   // frag tiles per wave
  constexpr int NA = BM / 64, NB = BN / 64;   // staging iters (256 thr x 16B)
  __shared__ __align__(16) short Asl[BM * 32];  // fragment-ordered
  __shared__ __align__(16) short Bsl[BN * 32];
  const int t = threadIdx.x;
  const int lane = t & 63, wave = t >> 6;

  // XCD-aware bijective swizzle of the flat block id
  const int gx = gridDim.x, gy = gridDim.y;
  const int nwg = gx * gy * (int)gridDim.z;
  int flat = (int)blockIdx.x + gx * ((int)blockIdx.y + gy * (int)blockIdx.z);
  flat = (flat & 7) * (nwg >> 3) + (flat >> 3);
  const int bx = flat % gx;
  const int rem = flat / gx;
  const int by = rem % gy;
  const int bz = rem / gy;

  const int m0 = by * BM, n0 = bx * BN;
  A += sA * bz;
  B += sB * bz;

  // staging: chunk s covers row = (s>>6)*16 + (s&15), k-quad q = (s>>4)&3
  const short* ga[NA];
  const short* gb[NB];
  short* la[NA];
  short* lb[NB];
#pragma unroll
  for (int i = 0; i < NA; ++i) {
    const int s = i * 256 + t;
    const int row = ((s >> 6) * 16) + (s & 15);
    const int q = (s >> 4) & 3;
    ga[i] = A + (size_t)(m0 + row) * lda + q * 8;
    la[i] = Asl + s * 8;
  }
#pragma unroll
  for (int i = 0; i < NB; ++i) {
    const int s = i * 256 + t;
    const int row = ((s >> 6) * 16) + (s & 15);
    const int q = (s >> 4) & 3;
    gb[i] = B + (size_t)(n0 + row) * ldb + q * 8;
    lb[i] = Bsl + s * 8;
  }

  f32x4 acc[FM][FN] = {};
  const int wm = wave & 1, wn = wave >> 1;

  for (int k0 = 0; k0 < K; k0 += 32) {
#pragma unroll
    for (int i = 0; i < NA; ++i) {
      __builtin_amdgcn_global_load_lds((const GLOBAL_AS void*)ga[i],
                                       (LDS_AS void*)la[i], 16, 0, 0);
      ga[i] += 32;
    }
#pragma unroll
    for (int i = 0; i < NB; ++i) {
      __builtin_amdgcn_global_load_lds((const GLOBAL_AS void*)gb[i],
                                       (LDS_AS void*)lb[i], 16, 0, 0);
      gb[i] += 32;
    }
    __syncthreads();
    s16x8 af[FM], bf[FN];
#pragma unroll
    for (int i = 0; i < FM; ++i)
      af[i] = *(const s16x8*)(Asl + (wm * FM + i) * 512 + lane * 8);
#pragma unroll
    for (int i = 0; i < FN; ++i)
      bf[i] = *(const s16x8*)(Bsl + (wn * FN + i) * 512 + lane * 8);
#pragma unroll
    for (int im = 0; im < FM; ++im)
#pragma unroll
      for (int in = 0; in < FN; ++in)
        acc[im][in] = __builtin_amdgcn_mfma_f32_16x16x32_bf16(
            af[im], bf[in], acc[im][in], 0, 0, 0);
    __syncthreads();
  }

  // epilogue. C/D frag: row m = quad*4+r, col n = lane&15 (within 16x16 tile)
  const int quad = lane >> 4, nn = lane & 15;
  if (EPI == 1) {
    // P = exp(S*alpha) bf16; per-row partial sums -> atomicAdd l[m]
    short* Cs = (short*)Cp + sC * bz;
    float* L = (float*)C2p + sC2 * bz;
#pragma unroll
    for (int im = 0; im < FM; ++im) {
      const int m = m0 + (wm * FM + im) * 16 + quad * 4;
      float rs[4] = {0.f, 0.f, 0.f, 0.f};
#pragma unroll
      for (int in = 0; in < FN; ++in) {
        const int n = n0 + (wn * FN + in) * 16 + nn;
#pragma unroll
        for (int r = 0; r < 4; ++r) {
          const float e = __expf(acc[im][in][r] * alpha);
          rs[r] += e;
          Cs[(size_t)(m + r) * ldc + n] = f2bf(e);
        }
      }
      // reduce across the 16 nn-lanes (same quad), then one atomic per row
#pragma unroll
      for (int off = 1; off < 16; off <<= 1)
#pragma unroll
        for (int r = 0; r < 4; ++r) rs[r] += __shfl_xor(rs[r], off, 64);
      if (nn == 0) {
#pragma unroll
        for (int r = 0; r < 4; ++r) atomicAdd(&L[m + r], rs[r]);
      }
    }
    return;
  }
#pragma unroll
  for (int im = 0; im < FM; ++im) {
    float invl[4];
    if (EPI == 2) {
      const float* L = resid + sR * bz;
      const int m = m0 + (wm * FM + im) * 16 + quad * 4;
#pragma unroll
      for (int r = 0; r < 4; ++r) invl[r] = 1.0f / L[m + r];
    }
#pragma unroll
    for (int in = 0; in < FN; ++in) {
      const int m = m0 + (wm * FM + im) * 16 + quad * 4;
      const int n = n0 + (wn * FN + in) * 16 + nn;
      if (EPI == 0) {
        if (m0 < 1024) {
          short* Cq = (short*)Cp + sC * bz;
          short o[4];
#pragma unroll
          for (int r = 0; r < 4; ++r) o[r] = f2bf(acc[im][in][r] + bias[m + r]);
          *(uint2*)(Cq + (size_t)n * ldc + m) = *(const uint2*)o;
        } else {
          short* Cv = (short*)C2p + sC2 * bz;
#pragma unroll
          for (int r = 0; r < 4; ++r)
            Cv[(size_t)(m - 1024 + r) * ldc + n] =
                f2bf(acc[im][in][r] + bias[m + r]);
        }
      } else if (EPI == 2) {
        short* Cs = (short*)Cp + sC * bz;
#pragma unroll
        for (int r = 0; r < 4; ++r)
          Cs[(size_t)(m + r) * ldc + n] = f2bf(acc[im][in][r] * invl[r]);
      } else {
        float* Cf = (float*)Cp + sC * bz;
        const float* R = resid + sR * bz;
#pragma unroll
        for (int r = 0; r < 4; ++r)
          Cf[(size_t)(m + r) * ldc + n] =
              acc[im][in][r] + bias[m + r] + R[(size_t)(m + r) * ldc + n];
      }
    }
  }
}

// ---------------- launch ----------------
extern "C" void kernel_launch(void* const* d_in, const int* in_sizes, int n_in,
                              void* d_out, int out_size, void* d_ws,
                              size_t ws_size, hipStream_t stream) {
  const float* x = (const float*)d_in[0];
  const float* gnw = (const float*)d_in[1];
  const float* gnb = (const float*)d_in[2];
  const float* qkvw = (const float*)d_in[3];   // [1536, 512]
  const float* qkvb = (const float*)d_in[4];   // [1536]
  const float* projw = (const float*)d_in[5];  // [512, 512]
  const float* projb = (const float*)d_in[6];  // [512]
  float* out = (float*)d_out;

  char* ws = (char*)d_ws;
  short* xnt = (short*)ws;                     //  8 MiB [b][1024 pix][512 c] bf16
  short* qkt = (short*)(ws + (8ull << 20));    // 16 MiB [b][1024 pix][1024: Q|K] bf16
  short* vbuf = (short*)(ws + (24ull << 20));  //  8 MiB [b][512 c][1024 pix] bf16
  short* Pbuf = (short*)(ws + (32ull << 20));  // 16 MiB [b][1024 i][1024 j] bf16 (unnormalized)
  short* Ot = (short*)(ws + (48ull << 20));    //  8 MiB [b][1024 pix][512 c] bf16
  short* wq = (short*)(ws + (56ull << 20));    // 1.5 MiB
  short* wp = (short*)(ws + (58ull << 20));    // 0.5 MiB
  float* lsum = (float*)(ws + (60ull << 20));  // 32 KiB [b][1024] softmax denominators

  // GroupNorm + weights->bf16 + zero lsum, one dispatch
  prep_kernel<<<1281, 256, 0, stream>>>(x, gnw, gnb, xnt, qkvw, wq, 1536 * 512,
                                        projw, wp, 512 * 512, lsum);

  // QKV: C[m][n] = sum_k wq[m][k] xnt[n][k]; M=1536 N=1024 K=512
  //   m<1024 -> qkt[n][m]; m>=1024 -> v[m-1024][n]   (nwg=1536 -> 6 blocks/CU)
  mfma_gemm<128, 64, 0><<<dim3(16, 12, Bsz), 256, 0, stream>>>(
      wq, xnt, 512, 512, 512, 0L, 1024L * 512, qkvb, 1.0f, qkt, 1024L * 1024,
      1024, vbuf, 512L * 1024, nullptr, 0L);

  // QK + softmax-numerator: P[i][j] = exp(scale * sum_k Q[i][k] K[j][k]),
  // row sums accumulated into lsum. M=N=1024 K=512   (nwg=1024 -> 4 blocks/CU)
  const float scale = 1.0f / sqrtf(512.0f);
  mfma_gemm<128, 64, 1><<<dim3(16, 8, Bsz), 256, 0, stream>>>(
      qkt, qkt + 512, 512, 1024, 1024, 1024L * 1024, 1024L * 1024, nullptr,
      scale, Pbuf, 1024L * 1024, 1024, lsum, 1024L, nullptr, 0L);

  // PV + normalize: Ot[i][c] = (sum_j P[i][j] V[c][j]) / l[i]; M=1024 N=512 K=1024
  // (nwg=1024 -> 4 blocks/CU)
  mfma_gemm<64, 64, 2><<<dim3(8, 16, Bsz), 256, 0, stream>>>(
      Pbuf, vbuf, 1024, 1024, 1024, 1024L * 1024, 512L * 1024, nullptr, 1.0f,
      Ot, 1024L * 512, 512, nullptr, 0L, lsum, 1024L);

  // out[o][i] = sum_c wp[o][c] Ot[i][c] + projb[o] + x[o][i]; M=512 N=1024 K=512
  // (nwg=1024 -> 4 blocks/CU)
  mfma_gemm<64, 64, 3><<<dim3(16, 8, Bsz), 256, 0, stream>>>(
      wp, Ot, 512, 512, 512, 0L, 1024L * 512, projb, 1.0f, out, 512L * 1024,
      1024, nullptr, 0L, x, 512L * 1024);
}

// Round 7
// 193.482 us; speedup vs baseline: 1.1455x; 1.1455x over previous
//
#include <hip/hip_runtime.h>
#include <cmath>

// Problem: x [8, 512, 32, 32] fp32. GroupNorm(32) -> QKV 1x1 -> attention -> proj 1x1 -> +x
constexpr int Bsz = 8, Cch = 512, NPIX = 1024;
constexpr int NG = 32, CPG = 16;

typedef __attribute__((ext_vector_type(4))) float f32x4;
typedef __attribute__((ext_vector_type(8))) short s16x8;

#define GLOBAL_AS __attribute__((address_space(1)))
#define LDS_AS __attribute__((address_space(3)))

__device__ inline short f2bf(float f) {  // RNE fp32 -> bf16
  union { float f; unsigned u; } c = {f};
  unsigned r = (c.u + 0x7fffu + ((c.u >> 16) & 1u)) >> 16;
  return (short)r;
}

__device__ inline float wave_reduce_sum(float v) {
#pragma unroll
  for (int off = 32; off > 0; off >>= 1) v += __shfl_xor(v, off, 64);
  return v;
}

// ---- fused: GroupNorm (blocks 0..255) + weight cvt (256..1279) + zero-l (1280) ----
// GroupNorm writes TRANSPOSED bf16 xnt[b][pix][c].
__global__ __launch_bounds__(256) void prep_kernel(
    const float* __restrict__ x, const float* __restrict__ w,
    const float* __restrict__ bb, short* __restrict__ xnt,
    const float* __restrict__ in1, short* __restrict__ out1, int n1,
    const float* __restrict__ in2, short* __restrict__ out2, int n2,
    float* __restrict__ lsum) {
  __shared__ float sm[8];
  if (blockIdx.x == 1280) {  // ---- zero the softmax denominators [8][1024] ----
    float4 z = {0.f, 0.f, 0.f, 0.f};
    float4* p = (float4*)lsum;
#pragma unroll
    for (int i = 0; i < 8; ++i) p[threadIdx.x + i * 256] = z;
    return;
  }
  if (blockIdx.x >= 256) {  // ---- weight fp32 -> bf16 conversion ----
    const int i = ((blockIdx.x - 256) * 256 + threadIdx.x) * 4;
    const float* in = in1;
    short* out = out1;
    int j = i;
    if (i >= n1) { in = in2; out = out2; j = i - n1; }
    if (j + 3 < (i >= n1 ? n2 : n1)) {
      float4 v = *(const float4*)(in + j);
      short o[4] = {f2bf(v.x), f2bf(v.y), f2bf(v.z), f2bf(v.w)};
      *(uint2*)(out + j) = *(const uint2*)o;
    }
    return;
  }
  // ---- GroupNorm ----
  const int bg = blockIdx.x, b = bg >> 5, g = bg & 31;
  const float* xp = x + ((size_t)(b * Cch + g * CPG)) * NPIX;
  float s = 0.f, ss = 0.f;
  for (int i = threadIdx.x * 4; i < CPG * NPIX; i += 1024) {
    float4 v = *(const float4*)(xp + i);
    s += v.x + v.y + v.z + v.w;
    ss += v.x * v.x + v.y * v.y + v.z * v.z + v.w * v.w;
  }
  s = wave_reduce_sum(s);
  ss = wave_reduce_sum(ss);
  const int wv = threadIdx.x >> 6;
  if ((threadIdx.x & 63) == 0) { sm[wv] = s; sm[4 + wv] = ss; }
  __syncthreads();
  const float tsum = sm[0] + sm[1] + sm[2] + sm[3];
  const float tsq = sm[4] + sm[5] + sm[6] + sm[7];
  const float inv_n = 1.0f / (CPG * NPIX);
  const float mean = tsum * inv_n;
  const float rstd = rsqrtf(tsq * inv_n - mean * mean + 1e-5f);
  float wc[CPG], bc[CPG];
#pragma unroll
  for (int c = 0; c < CPG; ++c) {
    wc[c] = w[g * CPG + c] * rstd;
    bc[c] = bb[g * CPG + c] - mean * wc[c];
  }
  // second pass: 4 pixels/thread, float4 reads (fully coalesced), register transpose
  const int p0 = threadIdx.x * 4;
  short ov[4][CPG];
#pragma unroll
  for (int c = 0; c < CPG; ++c) {
    float4 v = *(const float4*)(xp + (size_t)c * NPIX + p0);
    ov[0][c] = f2bf(v.x * wc[c] + bc[c]);
    ov[1][c] = f2bf(v.y * wc[c] + bc[c]);
    ov[2][c] = f2bf(v.z * wc[c] + bc[c]);
    ov[3][c] = f2bf(v.w * wc[c] + bc[c]);
  }
#pragma unroll
  for (int j = 0; j < 4; ++j) {
    short* op = xnt + ((size_t)(b * NPIX + p0 + j)) * Cch + g * CPG;
    *(uint4*)op = *(const uint4*)&ov[j][0];
    *(uint4*)(op + 8) = *(const uint4*)&ov[j][8];
  }
}

// ---------------- bf16 MFMA GEMM: 3-deep counted-vmcnt pipeline (T4) ----------------
// C[m][n] = sum_k A[m][k]*B[n][k], both row-major k-contiguous. 256 thr = 2x2 waves.
// K-loop: NBUF=3 LDS buffers, BK=32. Per iter:
//   [s_barrier]                      <- readers of the slot we're about to overwrite done
//   stage(t+2 -> slot)               <- loads stay IN FLIGHT across barriers
//   s_waitcnt vmcnt(2*(NA+NB)); s_barrier   <- tile t landed (issued 2 iters ago: ~free)
//   ds_read frags + MFMA             <- compiler inserts fine lgkmcnt
// No vmcnt(0) drain until the last tile. This is the m218 counted-vmcnt fix for the
// phase-locked drain that R2 (dbuf+__syncthreads) and R6 (occupancy) could not touch.
// XCD-chunked block swizzle (T1, bijective, nwg%8==0) kept from R5.
// EPI 0: qkv split -> m<1024: bf16 Cq[n*ldc+m] (+bias); else bf16 C2[(m-1024)*ldc+n] (+bias)
// EPI 1: softmax-fused QK: bf16 C[m*ldc+n] = exp(acc*alpha); row-sums atomicAdd to (float*)C2p
// EPI 2: PV: bf16 C[m*ldc+n] = acc / l[m]   (l passed via resid)
// EPI 3: fp32 C[m*ldc+n] = acc + bias[m] + resid[m*ldc+n]
template <int BM, int BN, int EPI>
__global__ __launch_bounds__(256) void mfma_gemm(
    const short* __restrict__ A, const short* __restrict__ B, int K, int lda,
    int ldb, long sA, long sB, const float* __restrict__ bias, float alpha,
    void* __restrict__ Cp, long sC, int ldc, void* __restrict__ C2p, long sC2,
    const float* __restrict__ resid, long sR) {
  constexpr int FM = BM / 32, FN = BN / 32;   // frag tiles per wave
  constexpr int NA = BM / 64, NB = BN / 64;   // staging insts (256 thr x 16B)
  constexpr int ASZ = BM * 32, BSZ = BN * 32; // shorts per buffer
  constexpr int NBUF = 3;
  __shared__ __align__(16) short Asl[NBUF * ASZ];  // fragment-ordered
  __shared__ __align__(16) short Bsl[NBUF * BSZ];
  const int t = threadIdx.x;
  const int lane = t & 63, wave = t >> 6;

  // XCD-aware bijective swizzle of the flat block id
  const int gx = gridDim.x, gy = gridDim.y;
  const int nwg = gx * gy * (int)gridDim.z;
  int flat = (int)blockIdx.x + gx * ((int)blockIdx.y + gy * (int)blockIdx.z);
  flat = (flat & 7) * (nwg >> 3) + (flat >> 3);
  const int bx = flat % gx;
  const int rem = flat / gx;
  const int by = rem % gy;
  const int bz = rem / gy;

  const int m0 = by * BM, n0 = bx * BN;
  A += sA * bz;
  B += sB * bz;

  // staging: chunk s covers row = (s>>6)*16 + (s&15), k-quad q = (s>>4)&3
  const short* ga[NA];
  const short* gb[NB];
  short* la[NA];
  short* lb[NB];
#pragma unroll
  for (int i = 0; i < NA; ++i) {
    const int s = i * 256 + t;
    const int row = ((s >> 6) * 16) + (s & 15);
    const int q = (s >> 4) & 3;
    ga[i] = A + (size_t)(m0 + row) * lda + q * 8;
    la[i] = Asl + s * 8;
  }
#pragma unroll
  for (int i = 0; i < NB; ++i) {
    const int s = i * 256 + t;
    const int row = ((s >> 6) * 16) + (s & 15);
    const int q = (s >> 4) & 3;
    gb[i] = B + (size_t)(n0 + row) * ldb + q * 8;
    lb[i] = Bsl + s * 8;
  }

  auto stage = [&](int slot) {
#pragma unroll
    for (int i = 0; i < NA; ++i) {
      __builtin_amdgcn_global_load_lds((const GLOBAL_AS void*)ga[i],
                                       (LDS_AS void*)(la[i] + slot * ASZ), 16,
                                       0, 0);
      ga[i] += 32;
    }
#pragma unroll
    for (int i = 0; i < NB; ++i) {
      __builtin_amdgcn_global_load_lds((const GLOBAL_AS void*)gb[i],
                                       (LDS_AS void*)(lb[i] + slot * BSZ), 16,
                                       0, 0);
      gb[i] += 32;
    }
  };

  f32x4 acc[FM][FN] = {};
  const int wm = wave & 1, wn = wave >> 1;
  const int NT = K >> 5;  // BK=32 tiles; NT >= 3 for all our shapes

  stage(0);
  stage(1);
  int cs = 0, ps = 2;
  for (int kt = 0; kt < NT; ++kt) {
    // readers of buf[ps] (tile kt-1's compute) are done -> safe to overwrite
    asm volatile("s_barrier" ::: "memory");
    if (kt + 2 < NT) {
      stage(ps);
      // wait for tile kt only; tiles kt+1, kt+2 stay in flight
      asm volatile("s_waitcnt vmcnt(%0)\n\ts_barrier" ::"n"(2 * (NA + NB))
                   : "memory");
    } else if (kt + 1 < NT) {
      asm volatile("s_waitcnt vmcnt(%0)\n\ts_barrier" ::"n"(NA + NB)
                   : "memory");
    } else {
      asm volatile("s_waitcnt vmcnt(0)\n\ts_barrier" ::: "memory");
    }
    const short* Ab = Asl + cs * ASZ;
    const short* Bb = Bsl + cs * BSZ;
    s16x8 af[FM], bf[FN];
#pragma unroll
    for (int i = 0; i < FM; ++i)
      af[i] = *(const s16x8*)(Ab + (wm * FM + i) * 512 + lane * 8);
#pragma unroll
    for (int i = 0; i < FN; ++i)
      bf[i] = *(const s16x8*)(Bb + (wn * FN + i) * 512 + lane * 8);
#pragma unroll
    for (int im = 0; im < FM; ++im)
#pragma unroll
      for (int in = 0; in < FN; ++in)
        acc[im][in] = __builtin_amdgcn_mfma_f32_16x16x32_bf16(
            af[im], bf[in], acc[im][in], 0, 0, 0);
    cs = (cs + 1 == NBUF) ? 0 : cs + 1;
    ps = (ps + 1 == NBUF) ? 0 : ps + 1;
  }

  // epilogue. C/D frag: row m = quad*4+r, col n = lane&15 (within 16x16 tile)
  const int quad = lane >> 4, nn = lane & 15;
  if (EPI == 1) {
    // P = exp(S*alpha) bf16; per-row partial sums -> atomicAdd l[m]
    short* Cs = (short*)Cp + sC * bz;
    float* L = (float*)C2p + sC2 * bz;
#pragma unroll
    for (int im = 0; im < FM; ++im) {
      const int m = m0 + (wm * FM + im) * 16 + quad * 4;
      float rs[4] = {0.f, 0.f, 0.f, 0.f};
#pragma unroll
      for (int in = 0; in < FN; ++in) {
        const int n = n0 + (wn * FN + in) * 16 + nn;
#pragma unroll
        for (int r = 0; r < 4; ++r) {
          const float e = __expf(acc[im][in][r] * alpha);
          rs[r] += e;
          Cs[(size_t)(m + r) * ldc + n] = f2bf(e);
        }
      }
      // reduce across the 16 nn-lanes (same quad), then one atomic per row
#pragma unroll
      for (int off = 1; off < 16; off <<= 1)
#pragma unroll
        for (int r = 0; r < 4; ++r) rs[r] += __shfl_xor(rs[r], off, 64);
      if (nn == 0) {
#pragma unroll
        for (int r = 0; r < 4; ++r) atomicAdd(&L[m + r], rs[r]);
      }
    }
    return;
  }
#pragma unroll
  for (int im = 0; im < FM; ++im) {
    float invl[4];
    if (EPI == 2) {
      const float* L = resid + sR * bz;
      const int m = m0 + (wm * FM + im) * 16 + quad * 4;
#pragma unroll
      for (int r = 0; r < 4; ++r) invl[r] = 1.0f / L[m + r];
    }
#pragma unroll
    for (int in = 0; in < FN; ++in) {
      const int m = m0 + (wm * FM + im) * 16 + quad * 4;
      const int n = n0 + (wn * FN + in) * 16 + nn;
      if (EPI == 0) {
        if (m0 < 1024) {
          short* Cq = (short*)Cp + sC * bz;
          short o[4];
#pragma unroll
          for (int r = 0; r < 4; ++r) o[r] = f2bf(acc[im][in][r] + bias[m + r]);
          *(uint2*)(Cq + (size_t)n * ldc + m) = *(const uint2*)o;
        } else {
          short* Cv = (short*)C2p + sC2 * bz;
#pragma unroll
          for (int r = 0; r < 4; ++r)
            Cv[(size_t)(m - 1024 + r) * ldc + n] =
                f2bf(acc[im][in][r] + bias[m + r]);
        }
      } else if (EPI == 2) {
        short* Cs = (short*)Cp + sC * bz;
#pragma unroll
        for (int r = 0; r < 4; ++r)
          Cs[(size_t)(m + r) * ldc + n] = f2bf(acc[im][in][r] * invl[r]);
      } else {
        float* Cf = (float*)Cp + sC * bz;
        const float* R = resid + sR * bz;
#pragma unroll
        for (int r = 0; r < 4; ++r)
          Cf[(size_t)(m + r) * ldc + n] =
              acc[im][in][r] + bias[m + r] + R[(size_t)(m + r) * ldc + n];
      }
    }
  }
}

// ---------------- launch ----------------
extern "C" void kernel_launch(void* const* d_in, const int* in_sizes, int n_in,
                              void* d_out, int out_size, void* d_ws,
                              size_t ws_size, hipStream_t stream) {
  const float* x = (const float*)d_in[0];
  const float* gnw = (const float*)d_in[1];
  const float* gnb = (const float*)d_in[2];
  const float* qkvw = (const float*)d_in[3];   // [1536, 512]
  const float* qkvb = (const float*)d_in[4];   // [1536]
  const float* projw = (const float*)d_in[5];  // [512, 512]
  const float* projb = (const float*)d_in[6];  // [512]
  float* out = (float*)d_out;

  char* ws = (char*)d_ws;
  short* xnt = (short*)ws;                     //  8 MiB [b][1024 pix][512 c] bf16
  short* qkt = (short*)(ws + (8ull << 20));    // 16 MiB [b][1024 pix][1024: Q|K] bf16
  short* vbuf = (short*)(ws + (24ull << 20));  //  8 MiB [b][512 c][1024 pix] bf16
  short* Pbuf = (short*)(ws + (32ull << 20));  // 16 MiB [b][1024 i][1024 j] bf16 (unnormalized)
  short* Ot = (short*)(ws + (48ull << 20));    //  8 MiB [b][1024 pix][512 c] bf16
  short* wq = (short*)(ws + (56ull << 20));    // 1.5 MiB
  short* wp = (short*)(ws + (58ull << 20));    // 0.5 MiB
  float* lsum = (float*)(ws + (60ull << 20));  // 32 KiB [b][1024] softmax denominators

  // GroupNorm + weights->bf16 + zero lsum, one dispatch
  prep_kernel<<<1281, 256, 0, stream>>>(x, gnw, gnb, xnt, qkvw, wq, 1536 * 512,
                                        projw, wp, 512 * 512, lsum);

  // QKV: C[m][n] = sum_k wq[m][k] xnt[n][k]; M=1536 N=1024 K=512
  //   m<1024 -> qkt[n][m]; m>=1024 -> v[m-1024][n]   (nwg=768, %8==0)
  mfma_gemm<128, 128, 0><<<dim3(8, 12, Bsz), 256, 0, stream>>>(
      wq, xnt, 512, 512, 512, 0L, 1024L * 512, qkvb, 1.0f, qkt, 1024L * 1024,
      1024, vbuf, 512L * 1024, nullptr, 0L);

  // QK + softmax-numerator: P[i][j] = exp(scale * sum_k Q[i][k] K[j][k]),
  // row sums accumulated into lsum. M=N=1024 K=512   (nwg=512)
  const float scale = 1.0f / sqrtf(512.0f);
  mfma_gemm<128, 128, 1><<<dim3(8, 8, Bsz), 256, 0, stream>>>(
      qkt, qkt + 512, 512, 1024, 1024, 1024L * 1024, 1024L * 1024, nullptr,
      scale, Pbuf, 1024L * 1024, 1024, lsum, 1024L, nullptr, 0L);

  // PV + normalize: Ot[i][c] = (sum_j P[i][j] V[c][j]) / l[i]; M=1024 N=512 K=1024
  // (nwg=512)
  mfma_gemm<128, 64, 2><<<dim3(8, 8, Bsz), 256, 0, stream>>>(
      Pbuf, vbuf, 1024, 1024, 1024, 1024L * 1024, 512L * 1024, nullptr, 1.0f,
      Ot, 1024L * 512, 512, nullptr, 0L, lsum, 1024L);

  // out[o][i] = sum_c wp[o][c] Ot[i][c] + projb[o] + x[o][i]; M=512 N=1024 K=512
  // (nwg=512)
  mfma_gemm<64, 128, 3><<<dim3(8, 8, Bsz), 256, 0, stream>>>(
      wp, Ot, 512, 512, 512, 0L, 1024L * 512, projb, 1.0f, out, 512L * 1024,
      1024, nullptr, 0L, x, 512L * 1024);
}